// Round 1
// 150.049 us; speedup vs baseline: 1.0046x; 1.0046x over previous
//
#include <hip/hip_runtime.h>
#include <math.h>

// Problem: D=8, H=64, W=64 -> 32768 pixels, 1024 gaussians, K=256
#define NG    1024
#define KD    256
#define NPIX  32768
#define BLOCK 1024
#define NQUAD 8          // float4 pixel-groups per thread: NPIX/4/BLOCK

// -0.5 * log2(e): exp(-0.5*maha) == exp2(K2C*maha)
#define K2C   (-0.72134752044448170f)
#define TWOK2 (-1.44269504088896340f)

#if __has_builtin(__builtin_amdgcn_exp2f)
#define EXP2F(x) __builtin_amdgcn_exp2f(x)
#else
#define EXP2F(x) __expf((x) * 0.69314718055994531f)
#endif

__device__ __forceinline__ float softplus_f(float x) {
    // stable: max(x,0) + log1p(exp(-|x|)) — matches jax.nn.softplus
    return fmaxf(x, 0.0f) + log1pf(expf(-fabsf(x)));
}

__global__ __launch_bounds__(BLOCK)
void mvn_profile_kernel(const float* __restrict__ rep,
                        const float* __restrict__ mean_W,
                        const float* __restrict__ mean_b,
                        const float* __restrict__ scale_W,
                        const float* __restrict__ scale_b,
                        float* __restrict__ out)
{
    const int g    = blockIdx.x;   // one block per gaussian
    const int t    = threadIdx.x;
    const int w    = t >> 6;       // wave id 0..15
    const int lane = t & 63;

    __shared__ float s_dot[9];     // the 9 dot products
    __shared__ float s_par[12];    // broadcast params
    __shared__ float s_red[16];    // per-wave sum partials

    // ---- prelude: 9 dot-products of length 256; wave w owns dot w ----
    if (w < 9) {
        const float4* r4 = (const float4*)(rep + (size_t)g * KD);
        const float4* w4 = (w < 3) ? (const float4*)(mean_W + w * KD)
                                   : (const float4*)(scale_W + (w - 3) * KD);
        float4 a = r4[lane];       // 16B/lane, coalesced, 64*16B = row
        float4 b = w4[lane];
        float acc = a.x * b.x + a.y * b.y + a.z * b.z + a.w * b.w;
        #pragma unroll
        for (int off = 32; off >= 1; off >>= 1)
            acc += __shfl_xor(acc, off, 64);
        if (lane == 0) s_dot[w] = acc;
    }
    __syncthreads();

    if (t == 0) {
        float mx = s_dot[0] + mean_b[0];
        float my = s_dot[1] + mean_b[1];
        float mz = s_dot[2] + mean_b[2];
        float s0 = softplus_f(s_dot[3] + scale_b[0]) + 1e-6f;
        float s1 = softplus_f(s_dot[4] + scale_b[1]) + 1e-6f;  // L10
        float s2 = softplus_f(s_dot[5] + scale_b[2]) + 1e-6f;
        float s3 = softplus_f(s_dot[6] + scale_b[3]) + 1e-6f;  // L20
        float s4 = softplus_f(s_dot[7] + scale_b[4]) + 1e-6f;  // L21
        float s5 = softplus_f(s_dot[8] + scale_b[3 + 2]) + 1e-6f;
        float L00 = softplus_f(s0);
        float L11 = softplus_f(s2);
        float L22 = softplus_f(s5);
        float r00 = 1.0f / L00;
        float r11 = 1.0f / L11;
        float r22 = 1.0f / L22;
        // x-offset slopes of (y0,y1,y2): a0 = r00
        float a1 = -s1 * r00 * r11;
        float a2 = -(s3 * r00 + s4 * a1) * r22;
        float R  = r00 * r00 + a1 * a1 + a2 * a2;
        s_par[0]  = mx;  s_par[1]  = my;  s_par[2]  = mz;
        s_par[3]  = r00; s_par[4]  = s1;  s_par[5]  = r11;
        s_par[6]  = s3;  s_par[7]  = s4;  s_par[8]  = r22;
        s_par[9]  = a1;  s_par[10] = a2;  s_par[11] = K2C * R;   // RK
        // NOTE: no logs needed — softmax shift-invariance with m' = -c
        // makes the weight exactly exp(-maha/2); log_det cancels.
    }
    __syncthreads();

    const float mx  = s_par[0], my  = s_par[1], mz  = s_par[2];
    const float r00 = s_par[3], L10 = s_par[4], r11 = s_par[5];
    const float L20 = s_par[6], L21 = s_par[7], r22 = s_par[8];
    const float a1  = s_par[9], a2  = s_par[10], RK = s_par[11];

    // ---- thread geometry: pixel p = 4*(t + 1024*i) + d ----
    //   x = 4*(t&15) + d   (thread-const base, d = 0..3 within float4)
    //   y = t >> 4         (thread-const)
    //   z = i              (loop index, 0..7)
    const float px0 = (float)((t & 15) << 2) - 31.5f;
    const float py  = (float)(t >> 4) - 31.5f;
    const float y0  = (px0 - mx) * r00;
    const float y1  = (py - my - L10 * y0) * r11;
    const float zc  = (-3.5f - mz - L20 * y0 - L21 * y1) * r22; // y2_i = zc + i*r22
    const float c0  = fmaf(y0, y0, y1 * y1);   // P const part
    const float qc  = fmaf(y0, r00, y1 * a1);  // Q const part (a0 = r00)

    // ---- single pass: maha_d = P + 2dQ + d^2 R (exact quadratic in x-offset d)
    //      e = exp2(K2C * maha); track sum. No max pass needed (maha >= 0). ----
    float4 e[NQUAD];
    float lsum = 0.0f;
    #pragma unroll
    for (int i = 0; i < NQUAD; ++i) {
        float y2 = fmaf((float)i, r22, zc);
        float P  = fmaf(y2, y2, c0);
        float Q  = fmaf(y2, a2, qc);
        float kP = K2C * P;
        float QK = TWOK2 * Q;
        float4 v;
        v.x = EXP2F(kP);
        v.y = EXP2F(fmaf(1.0f, fmaf(1.0f, RK, QK), kP));
        v.z = EXP2F(fmaf(2.0f, fmaf(2.0f, RK, QK), kP));
        v.w = EXP2F(fmaf(3.0f, fmaf(3.0f, RK, QK), kP));
        e[i] = v;
        lsum += ((v.x + v.y) + (v.z + v.w));
    }

    // ---- block sum over 32768 weights ----
    #pragma unroll
    for (int off = 32; off >= 1; off >>= 1)
        lsum += __shfl_xor(lsum, off, 64);
    if (lane == 0) s_red[w] = lsum;
    __syncthreads();
    float S = 0.0f;
    #pragma unroll
    for (int k = 0; k < 16; ++k) S += s_red[k];
    const float scale = 1.0f / (S + 1e-10f);

    // ---- scale + float4 coalesced stores (16B/lane, 1KiB/wave-store) ----
    float4* op = (float4*)(out + (size_t)g * NPIX) + t;
    #pragma unroll
    for (int i = 0; i < NQUAD; ++i) {
        float4 v = e[i];
        v.x *= scale; v.y *= scale; v.z *= scale; v.w *= scale;
        op[i * BLOCK] = v;
    }
}

extern "C" void kernel_launch(void* const* d_in, const int* in_sizes, int n_in,
                              void* d_out, int out_size, void* d_ws, size_t ws_size,
                              hipStream_t stream) {
    const float* rep     = (const float*)d_in[0];
    const float* mean_W  = (const float*)d_in[1];
    const float* mean_b  = (const float*)d_in[2];
    const float* scale_W = (const float*)d_in[3];
    const float* scale_b = (const float*)d_in[4];
    float* out = (float*)d_out;

    hipLaunchKernelGGL(mvn_profile_kernel, dim3(NG), dim3(BLOCK), 0, stream,
                       rep, mean_W, mean_b, scale_W, scale_b, out);
}